// Round 9
// baseline (288.046 us; speedup 1.0000x reference)
//
#include <hip/hip_runtime.h>
#include <cmath>

// Problem constants (fixed by the reference)
constexpr int TOT = 131072;   // 32 graphs * 4096 nodes
constexpr int NE  = 1048576;  // edges
constexpr int NMASK = 4095;   // N-1, N=4096

// Bucketed adjacency
constexpr int NB   = 512;     // buckets (dst >> 8)
constexpr int DPB  = 256;     // dsts per bucket
constexpr int BCAP = 4096;    // slots per bucket (mean 2048)
constexpr int EPB  = 2048;    // edges per partition block

typedef __attribute__((ext_vector_type(8))) short bf16x8;
typedef __attribute__((ext_vector_type(4))) float f32x4;

// ---- bf16 helpers (RNE) ----
__device__ inline float bf2f(unsigned int u16) {
    union { unsigned int i; float f; } x; x.i = u16 << 16; return x.f;
}
__device__ inline unsigned short f2bf(float f) {
    union { float f; unsigned int i; } x; x.f = f;
    unsigned int r = (x.i + 0x7fffu + ((x.i >> 16) & 1u)) >> 16;
    return (unsigned short)r;
}
__device__ inline void unpack8(uint4 v, float* f) {
    f[0] = bf2f(v.x & 0xffffu); f[1] = bf2f(v.x >> 16);
    f[2] = bf2f(v.y & 0xffffu); f[3] = bf2f(v.y >> 16);
    f[4] = bf2f(v.z & 0xffffu); f[5] = bf2f(v.z >> 16);
    f[6] = bf2f(v.w & 0xffffu); f[7] = bf2f(v.w >> 16);
}
__device__ inline uint4 pack8(const float* f) {
    uint4 v;
    v.x = (unsigned)f2bf(f[0]) | ((unsigned)f2bf(f[1]) << 16);
    v.y = (unsigned)f2bf(f[2]) | ((unsigned)f2bf(f[3]) << 16);
    v.z = (unsigned)f2bf(f[4]) | ((unsigned)f2bf(f[5]) << 16);
    v.w = (unsigned)f2bf(f[6]) | ((unsigned)f2bf(f[7]) << 16);
    return v;
}

// ================= edge partition by dst bucket =================
__global__ __launch_bounds__(256) void k_part(const int* __restrict__ src,
                                              const int* __restrict__ dst,
                                              int* __restrict__ gcur,
                                              unsigned* __restrict__ buf) {
    __shared__ int hist[NB];
    __shared__ int cbase[NB];
    __shared__ int lcur[NB];
    const int tid = threadIdx.x;
    const int e0 = blockIdx.x * EPB;

    for (int b = tid; b < NB; b += 256) hist[b] = 0;
    __syncthreads();
    for (int i = tid; i < EPB; i += 256)
        atomicAdd(&hist[dst[e0 + i] >> 8], 1);
    __syncthreads();
    for (int b = tid; b < NB; b += 256) {
        int c = hist[b];
        cbase[b] = (c > 0) ? atomicAdd(&gcur[b * 32], c) : 0;
        lcur[b] = 0;
    }
    __syncthreads();
    for (int i = tid; i < EPB; i += 256) {
        int e = e0 + i;
        int d = dst[e];
        int b = d >> 8;
        int p = atomicAdd(&lcur[b], 1);
        buf[b * BCAP + cbase[b] + p] = ((unsigned)src[e] << 8) | (unsigned)(d & 255);
    }
}

// ================= per-bucket CSR build + dinv + fused x*dinv scaling =================
__global__ __launch_bounds__(256) void k_bcsr(const unsigned* __restrict__ buf,
                                              const int* __restrict__ gcur,
                                              int* __restrict__ adj,
                                              int2* __restrict__ rse,
                                              float* __restrict__ dinv,
                                              const float4* __restrict__ x,
                                              uint4* __restrict__ xsc) {
    __shared__ int cnt[DPB];
    __shared__ int start[DPB];
    __shared__ int cur[DPB];
    __shared__ int sc[DPB];
    const int b = blockIdx.x;
    const int tid = threadIdx.x;
    cnt[tid] = 0;
    __syncthreads();
    const int n = gcur[b * 32];
    const unsigned* eb = buf + b * BCAP;
    for (int i = tid; i < n; i += 256)
        atomicAdd(&cnt[eb[i] & 255u], 1);
    __syncthreads();
    int v = cnt[tid];
    sc[tid] = v;
    __syncthreads();
    for (int off = 1; off < 256; off <<= 1) {
        int a = sc[tid];
        int p = (tid >= off) ? sc[tid - off] : 0;
        __syncthreads();
        sc[tid] = a + p;
        __syncthreads();
    }
    int st = sc[tid] - v;
    start[tid] = st;
    cur[tid] = 0;
    int d = (b << 8) + tid;
    rse[d] = make_int2(b * BCAP + st, v);
    dinv[d] = rsqrtf((float)v + 1.0f);   // +1 self-loop
    __syncthreads();
    for (int i = tid; i < n; i += 256) {
        unsigned w = eb[i];
        int dl = (int)(w & 255u);
        int p = atomicAdd(&cur[dl], 1);
        adj[b * BCAP + start[dl] + p] = (int)(w >> 8);
    }
    // fused: xs = x * dinv -> bf16 for this bucket's 256 rows (cnt is stable)
    for (int i = tid; i < DPB * 8; i += 256) {
        int rl = i >> 3;
        int t = (b << 11) + i;                 // global uint4 index (row*8+g)
        float dv = rsqrtf((float)cnt[rl] + 1.0f);
        float4 v0 = x[t * 2], v1 = x[t * 2 + 1];
        float f[8] = { v0.x * dv, v0.y * dv, v0.z * dv, v0.w * dv,
                       v1.x * dv, v1.y * dv, v1.z * dv, v1.w * dv };
        xsc[t] = pack8(f);
    }
}

// ================= weight packing into MFMA B-fragment order =================
__global__ __launch_bounds__(256) void k_packall(
    const float* __restrict__ W1, const float* __restrict__ W2, const float* __restrict__ W3,
    const float* __restrict__ tW1, const float* __restrict__ tW2, const float* __restrict__ tW3,
    unsigned short* __restrict__ g1, unsigned short* __restrict__ g2, unsigned short* __restrict__ g3,
    unsigned short* __restrict__ c1, unsigned short* __restrict__ c2, unsigned short* __restrict__ c3) {
    int gid = blockIdx.x * 256 + threadIdx.x;
    const float* w; unsigned short* wp; int CIN, COUT, taps, idx;
    if      (gid <  8192) { w = W1;  wp = g1; CIN = 64;  COUT = 128; taps = 1; idx = gid; }
    else if (gid < 12288) { w = W2;  wp = g2; CIN = 128; COUT = 32;  taps = 1; idx = gid - 8192; }
    else if (gid < 16384) { w = W3;  wp = g3; CIN = 32;  COUT = 128; taps = 1; idx = gid - 12288; }
    else if (gid < 65536) { w = tW1; wp = c1; CIN = 128; COUT = 128; taps = 3; idx = gid - 16384; }
    else if (gid < 77824) { w = tW2; wp = c2; CIN = 128; COUT = 32;  taps = 3; idx = gid - 65536; }
    else if (gid < 90112) { w = tW3; wp = c3; CIN = 32;  COUT = 128; taps = 3; idx = gid - 77824; }
    else return;
    int j = idx & 7;
    int L = (idx >> 3) & 63;
    int f = idx >> 9;
    int NT = COUT >> 4;
    int kc = f / NT, nt = f - kc * NT;
    int k = kc * 32 + (L >> 4) * 8 + j;
    int n = nt * 16 + (L & 15);
    float v;
    if (taps == 1) v = w[k * COUT + n];
    else { int t = k / CIN, c = k - t * CIN; v = w[(n * CIN + c) * 3 + t]; }
    wp[idx] = f2bf(v);
}

// ================= standalone CSR gather (layer-2 epilogue) =================
// out = relu((self+sum)*dinv + bias) * dinv ; LC = log2(C/8) threads per row.
template<int LC>
__global__ __launch_bounds__(256) void k_gcsr(const uint4* __restrict__ xs,
                                              const int* __restrict__ adj,
                                              const int2* __restrict__ rse,
                                              const float* __restrict__ dinv,
                                              const float* __restrict__ bias,
                                              uint4* __restrict__ out) {
    int t = blockIdx.x * 256 + threadIdx.x;   // t < TOT << LC
    int d = t >> LC;
    int g = t & ((1 << LC) - 1);
    float a[8];
    unpack8(xs[t], a);                        // self-loop term
    int2 se = rse[d];
    int e = se.x, end = se.x + se.y;
    for (; e + 4 <= end; e += 4) {
        int s0 = adj[e], s1 = adj[e + 1], s2 = adj[e + 2], s3 = adj[e + 3];
        uint4 v0 = xs[(s0 << LC) + g];
        uint4 v1 = xs[(s1 << LC) + g];
        uint4 v2 = xs[(s2 << LC) + g];
        uint4 v3 = xs[(s3 << LC) + g];
        float f[8];
        unpack8(v0, f);
#pragma unroll
        for (int j = 0; j < 8; ++j) a[j] += f[j];
        unpack8(v1, f);
#pragma unroll
        for (int j = 0; j < 8; ++j) a[j] += f[j];
        unpack8(v2, f);
#pragma unroll
        for (int j = 0; j < 8; ++j) a[j] += f[j];
        unpack8(v3, f);
#pragma unroll
        for (int j = 0; j < 8; ++j) a[j] += f[j];
    }
    for (; e < end; ++e) {
        float f[8];
        unpack8(xs[(adj[e] << LC) + g], f);
#pragma unroll
        for (int j = 0; j < 8; ++j) a[j] += f[j];
    }
    float dv = dinv[d];
#pragma unroll
    for (int j = 0; j < 8; ++j)
        a[j] = fmaxf(fmaf(a[j], dv, bias[g * 8 + j]), 0.0f) * dv;
    out[t] = pack8(a);
}

// ================= fused gather + GEMM (CIN->128, TAPS=1) =================
template<int CIN, bool RELU>
__global__ __launch_bounds__(256) void k_gmm(const uint4* __restrict__ xs,
                                             const int* __restrict__ adj,
                                             const int2* __restrict__ rse,
                                             const float* __restrict__ dinv,
                                             const bf16x8* __restrict__ wp,
                                             const float* __restrict__ bias,
                                             unsigned short* __restrict__ y) {
    constexpr int COUT = 128;
    constexpr int ROWS = 64;
    constexpr int SC = CIN + 8;
    constexpr int NV = CIN / 8;           // uint4s per row
    constexpr int VPT = NV / 4;           // uint4s per thread (4 threads/row)
    constexpr int NK = CIN / 32;
    constexpr int NT = COUT / 16;
    constexpr int WN = 2, WM = 4;
    __shared__ __attribute__((aligned(16))) unsigned short tile[ROWS * SC];

    const int R0 = blockIdx.x * ROWS;
    const int tid = threadIdx.x;

    // ---- gather/stage phase (4-edge unroll: up to 4*VPT loads in flight) ----
    {
        int r = R0 + (tid >> 2);
        int g = tid & 3;
        const uint4* base = xs + (long)r * NV + g * VPT;
        float a[VPT * 8];
#pragma unroll
        for (int v = 0; v < VPT; ++v) unpack8(base[v], a + v * 8);   // self-loop
        int2 se = rse[r];
        int e = se.x, end = se.x + se.y;
        for (; e + 4 <= end; e += 4) {
            int s0 = adj[e], s1 = adj[e + 1], s2 = adj[e + 2], s3 = adj[e + 3];
            const uint4* p0 = xs + (long)s0 * NV + g * VPT;
            const uint4* p1 = xs + (long)s1 * NV + g * VPT;
            const uint4* p2 = xs + (long)s2 * NV + g * VPT;
            const uint4* p3 = xs + (long)s3 * NV + g * VPT;
            uint4 v0[VPT], v1[VPT], v2[VPT], v3[VPT];
#pragma unroll
            for (int v = 0; v < VPT; ++v) { v0[v] = p0[v]; v1[v] = p1[v]; v2[v] = p2[v]; v3[v] = p3[v]; }
            float f[VPT * 8];
#pragma unroll
            for (int v = 0; v < VPT; ++v) unpack8(v0[v], f + v * 8);
#pragma unroll
            for (int j = 0; j < VPT * 8; ++j) a[j] += f[j];
#pragma unroll
            for (int v = 0; v < VPT; ++v) unpack8(v1[v], f + v * 8);
#pragma unroll
            for (int j = 0; j < VPT * 8; ++j) a[j] += f[j];
#pragma unroll
            for (int v = 0; v < VPT; ++v) unpack8(v2[v], f + v * 8);
#pragma unroll
            for (int j = 0; j < VPT * 8; ++j) a[j] += f[j];
#pragma unroll
            for (int v = 0; v < VPT; ++v) unpack8(v3[v], f + v * 8);
#pragma unroll
            for (int j = 0; j < VPT * 8; ++j) a[j] += f[j];
        }
        for (; e < end; ++e) {
            const uint4* p0 = xs + (long)adj[e] * NV + g * VPT;
            float f[VPT * 8];
#pragma unroll
            for (int v = 0; v < VPT; ++v) unpack8(p0[v], f + v * 8);
#pragma unroll
            for (int j = 0; j < VPT * 8; ++j) a[j] += f[j];
        }
        float dv = dinv[r];
#pragma unroll
        for (int j = 0; j < VPT * 8; ++j) a[j] *= dv;
        uint4* dst4 = (uint4*)(tile + (tid >> 2) * SC + g * VPT * 8);
#pragma unroll
        for (int v = 0; v < VPT; ++v) dst4[v] = pack8(a + v * 8);
    }
    __syncthreads();

    // ---- MFMA phase ----
    const int lane = threadIdx.x & 63;
    const int w = threadIdx.x >> 6;
    const int l16 = lane & 15;
    const int q = lane >> 4;
    const int colbase = w * 32;
    const int nt0 = colbase >> 4;

    f32x4 acc[WM][WN];
#pragma unroll
    for (int wm = 0; wm < WM; ++wm)
#pragma unroll
        for (int nt = 0; nt < WN; ++nt) acc[wm][nt] = (f32x4){0.f, 0.f, 0.f, 0.f};

    const bf16x8* __restrict__ wpl = wp + lane;

#pragma unroll
    for (int kc = 0; kc < NK; ++kc) {
        bf16x8 a[WM];
#pragma unroll
        for (int wm = 0; wm < WM; ++wm)
            a[wm] = *(const bf16x8*)(tile + (wm * 16 + l16) * SC + kc * 32 + q * 8);
        bf16x8 b[WN];
#pragma unroll
        for (int nt = 0; nt < WN; ++nt)
            b[nt] = wpl[(kc * NT + nt0 + nt) * 64];
#pragma unroll
        for (int wm = 0; wm < WM; ++wm)
#pragma unroll
            for (int nt = 0; nt < WN; ++nt)
                acc[wm][nt] = __builtin_amdgcn_mfma_f32_16x16x32_bf16(a[wm], b[nt], acc[wm][nt], 0, 0, 0);
    }

#pragma unroll
    for (int wm = 0; wm < WM; ++wm) {
#pragma unroll
        for (int nt = 0; nt < WN; ++nt) {
            int col = colbase + nt * 16 + l16;
            float bi = bias[col];
#pragma unroll
            for (int r = 0; r < 4; ++r) {
                int row = R0 + wm * 16 + q * 4 + r;
                float v = acc[wm][nt][r] + bi;
                if (RELU) v = fmaxf(v, 0.0f);
                y[(long)row * COUT + col] = f2bf(v);
            }
        }
    }
}

// ================= MFMA dense GEMM (layer-2 projection 128->32) =================
template<int CIN, int COUT, bool SOUT>
__global__ __launch_bounds__(256) void k_mm(const unsigned short* __restrict__ x,
                                            const bf16x8* __restrict__ wp,
                                            const float* __restrict__ dinv,
                                            unsigned short* __restrict__ y) {
    constexpr int ROWS = 64;
    constexpr int SC = CIN + 8;
    constexpr int NK = CIN / 32;
    constexpr int NT = COUT / 16;
    constexpr int WN = 1, WM = 2;
    __shared__ __attribute__((aligned(16))) unsigned short tile[ROWS * SC];

    const int R0 = blockIdx.x * ROWS;

    constexpr int NLD = ROWS * (CIN / 8);
    for (int idx = threadIdx.x; idx < NLD; idx += 256) {
        int tr = idx / (CIN / 8);
        int c8 = idx - tr * (CIN / 8);
        uint4 v = *(const uint4*)(x + (long)(R0 + tr) * CIN + c8 * 8);
        *(uint4*)(tile + tr * SC + c8 * 8) = v;
    }
    __syncthreads();

    const int lane = threadIdx.x & 63;
    const int w = threadIdx.x >> 6;
    const int l16 = lane & 15;
    const int q = lane >> 4;
    const int colbase = (w & 1) * 16;
    const int rowbase = (w >> 1) * 32;
    const int nt0 = colbase >> 4;

    f32x4 acc[WM][WN];
#pragma unroll
    for (int wm = 0; wm < WM; ++wm)
#pragma unroll
        for (int nt = 0; nt < WN; ++nt) acc[wm][nt] = (f32x4){0.f, 0.f, 0.f, 0.f};

    const bf16x8* __restrict__ wpl = wp + lane;

#pragma unroll
    for (int kc = 0; kc < NK; ++kc) {
        bf16x8 a[WM];
#pragma unroll
        for (int wm = 0; wm < WM; ++wm)
            a[wm] = *(const bf16x8*)(tile + (rowbase + wm * 16 + l16) * SC + kc * 32 + q * 8);
        bf16x8 b[WN];
#pragma unroll
        for (int nt = 0; nt < WN; ++nt)
            b[nt] = wpl[(kc * NT + nt0 + nt) * 64];
#pragma unroll
        for (int wm = 0; wm < WM; ++wm)
#pragma unroll
            for (int nt = 0; nt < WN; ++nt)
                acc[wm][nt] = __builtin_amdgcn_mfma_f32_16x16x32_bf16(a[wm], b[nt], acc[wm][nt], 0, 0, 0);
    }

#pragma unroll
    for (int wm = 0; wm < WM; ++wm) {
#pragma unroll
        for (int nt = 0; nt < WN; ++nt) {
            int col = colbase + nt * 16 + l16;
#pragma unroll
            for (int r = 0; r < 4; ++r) {
                int row = R0 + rowbase + wm * 16 + q * 4 + r;
                float v = acc[wm][nt][r];
                if (SOUT) v *= dinv[row];
                y[(long)row * COUT + col] = f2bf(v);
            }
        }
    }
}

// ================= fused temporal conv1+conv2+conv3+heads =================
// All in-LDS: xin(82x136) -> conv1 -> c1(82x136) -> conv2 -> c2(66x40)
//   -> conv3 -> xts(64x130, aliased on xin) -> heads.
// Index identity: every conv reads its buffer at row index 16*rt + l16 + tap.
// Batch-boundary zero-padding via n-masking at each LDS write.
__global__ __launch_bounds__(256) void k_tconv_heads(
    const unsigned short* __restrict__ x,      // [TOT,128] bf16 (h3)
    const bf16x8* __restrict__ wp1, const float* __restrict__ tb1,
    const bf16x8* __restrict__ wp2, const float* __restrict__ tb2,
    const bf16x8* __restrict__ wp3, const float* __restrict__ tb3,
    const float* __restrict__ Wpi, const float* __restrict__ bpi,
    const float* __restrict__ Wn,  const float* __restrict__ bn,
    const float* __restrict__ Wp,  const float* __restrict__ bp,
    float* __restrict__ out) {
    constexpr int SC1 = 136;                  // 128 + 8
    constexpr int SC2 = 40;                   // 32 + 8
    __shared__ __attribute__((aligned(16))) unsigned short shl[82 * 136 * 2 + 66 * 40];
    unsigned short* xin = shl;                // 82 rows: global [R0-3, R0+79)
    unsigned short* c1  = shl + 82 * 136;     // 82 rows: global [R0-2, R0+80)
    unsigned short* c2  = shl + 2 * 82 * 136; // 66 rows: global [R0-1, R0+65)
    unsigned short* xts = shl;                // alias (xin dead after conv1)

    const int R0 = blockIdx.x * 64;
    const int n0 = R0 & NMASK;
    const int tid = threadIdx.x;

    // ---- stage xin (zero outside batch) ----
    for (int i = tid; i < 82 * 16; i += 256) {
        int r = i >> 4;
        int c8 = i & 15;
        int n = n0 - 3 + r;
        uint4 v = make_uint4(0, 0, 0, 0);
        if (n >= 0 && n < 4096)
            v = *(const uint4*)(x + (long)(R0 - 3 + r) * 128 + c8 * 8);
        *(uint4*)(xin + r * SC1 + c8 * 8) = v;
    }
    // zero c1 rows 80,81 (read by conv2's last tile, never written by conv1)
    for (int i = tid; i < 2 * 16; i += 256)
        *(uint4*)(c1 + (80 + (i >> 4)) * SC1 + (i & 15) * 8) = make_uint4(0, 0, 0, 0);
    __syncthreads();

    const int lane = tid & 63;
    const int w = tid >> 6;
    const int l16 = lane & 15;
    const int q = lane >> 4;

    // ---- conv1: 128->128, 5 row-tiles at [R0-2 + 16rt), wave cols {2w,2w+1} ----
    {
        f32x4 acc[5][2];
#pragma unroll
        for (int rt = 0; rt < 5; ++rt)
#pragma unroll
            for (int nt = 0; nt < 2; ++nt) acc[rt][nt] = (f32x4){0.f, 0.f, 0.f, 0.f};
        const bf16x8* wpl = wp1 + lane;
#pragma unroll
        for (int kc = 0; kc < 12; ++kc) {
            int tap = kc >> 2, ch = kc & 3;
            bf16x8 a[5];
#pragma unroll
            for (int rt = 0; rt < 5; ++rt)
                a[rt] = *(const bf16x8*)(xin + (16 * rt + l16 + tap) * SC1 + ch * 32 + q * 8);
            bf16x8 b[2];
#pragma unroll
            for (int nt = 0; nt < 2; ++nt)
                b[nt] = wpl[(kc * 8 + 2 * w + nt) * 64];
#pragma unroll
            for (int rt = 0; rt < 5; ++rt)
#pragma unroll
                for (int nt = 0; nt < 2; ++nt)
                    acc[rt][nt] = __builtin_amdgcn_mfma_f32_16x16x32_bf16(a[rt], b[nt], acc[rt][nt], 0, 0, 0);
        }
#pragma unroll
        for (int rt = 0; rt < 5; ++rt) {
#pragma unroll
            for (int nt = 0; nt < 2; ++nt) {
                int col = w * 32 + nt * 16 + l16;
                float bi = tb1[col];
#pragma unroll
                for (int r = 0; r < 4; ++r) {
                    int idx = 16 * rt + q * 4 + r;          // c1 row index
                    int n = n0 - 2 + idx;
                    unsigned short v = 0;
                    if (n >= 0 && n < 4096)
                        v = f2bf(fmaxf(acc[rt][nt][r] + bi, 0.0f));
                    c1[idx * SC1 + col] = v;
                }
            }
        }
    }
    __syncthreads();

    // ---- conv2: 128->32, 5 row-tiles at [R0-1 + 16rt), wave rts {w, w+4} ----
    for (int rt = w; rt < 5; rt += 4) {
        f32x4 acc[2];
#pragma unroll
        for (int nt = 0; nt < 2; ++nt) acc[nt] = (f32x4){0.f, 0.f, 0.f, 0.f};
        const bf16x8* wpl = wp2 + lane;
#pragma unroll
        for (int kc = 0; kc < 12; ++kc) {
            int tap = kc >> 2, ch = kc & 3;
            bf16x8 a = *(const bf16x8*)(c1 + (16 * rt + l16 + tap) * SC1 + ch * 32 + q * 8);
            bf16x8 b0 = wpl[(kc * 2 + 0) * 64];
            bf16x8 b1 = wpl[(kc * 2 + 1) * 64];
            acc[0] = __builtin_amdgcn_mfma_f32_16x16x32_bf16(a, b0, acc[0], 0, 0, 0);
            acc[1] = __builtin_amdgcn_mfma_f32_16x16x32_bf16(a, b1, acc[1], 0, 0, 0);
        }
#pragma unroll
        for (int nt = 0; nt < 2; ++nt) {
            int col = nt * 16 + l16;
            float bi = tb2[col];
#pragma unroll
            for (int r = 0; r < 4; ++r) {
                int idx = 16 * rt + q * 4 + r;              // c2 row index
                if (idx < 66) {
                    int n = n0 - 1 + idx;
                    unsigned short v = 0;
                    if (n >= 0 && n < 4096)
                        v = f2bf(fmaxf(acc[nt][r] + bi, 0.0f));
                    c2[idx * SC2 + col] = v;
                }
            }
        }
    }
    __syncthreads();

    // ---- conv3: 32->128, 4 row-tiles at R0, wave cols {2w,2w+1}; write xts ----
    {
        f32x4 acc[4][2];
#pragma unroll
        for (int rt = 0; rt < 4; ++rt)
#pragma unroll
            for (int nt = 0; nt < 2; ++nt) acc[rt][nt] = (f32x4){0.f, 0.f, 0.f, 0.f};
        const bf16x8* wpl = wp3 + lane;
#pragma unroll
        for (int kc = 0; kc < 3; ++kc) {
            bf16x8 a[4];
#pragma unroll
            for (int rt = 0; rt < 4; ++rt)
                a[rt] = *(const bf16x8*)(c2 + (16 * rt + l16 + kc) * SC2 + q * 8);
            bf16x8 b[2];
#pragma unroll
            for (int nt = 0; nt < 2; ++nt)
                b[nt] = wpl[(kc * 8 + 2 * w + nt) * 64];
#pragma unroll
            for (int rt = 0; rt < 4; ++rt)
#pragma unroll
                for (int nt = 0; nt < 2; ++nt)
                    acc[rt][nt] = __builtin_amdgcn_mfma_f32_16x16x32_bf16(a[rt], b[nt], acc[rt][nt], 0, 0, 0);
        }
        __syncthreads();   // all c2/xin reads done before xts (alias) writes
#pragma unroll
        for (int rt = 0; rt < 4; ++rt) {
#pragma unroll
            for (int nt = 0; nt < 2; ++nt) {
                int col = w * 32 + nt * 16 + l16;
                float bi = tb3[col];
#pragma unroll
                for (int r = 0; r < 4; ++r) {
                    int row = 16 * rt + q * 4 + r;
                    xts[row * 130 + col] = f2bf(fmaxf(acc[rt][nt][r] + bi, 0.0f));
                }
            }
        }
    }
    __syncthreads();

    // ---- heads ----
    if (tid < 192) {
        int h = tid >> 6;                      // wave-uniform
        int row = tid & 63;
        const float* Wh = (h == 0) ? Wpi : (h == 1) ? Wn : Wp;
        float s = 0.0f;
        const unsigned short* xr = xts + row * 130;
#pragma unroll
        for (int c2i = 0; c2i < 64; ++c2i) {
            unsigned u = *(const unsigned*)(xr + c2i * 2);
            s = fmaf(bf2f(u & 0xffffu), Wh[c2i * 2], s);
            s = fmaf(bf2f(u >> 16), Wh[c2i * 2 + 1], s);
        }
        float bb = (h == 0) ? bpi[0] : (h == 1) ? bn[0] : bp[0];
        float z = s + bb;
        float o;
        if (h == 1) o = (z > 20.0f) ? z : log1pf(expf(z));
        else        o = 1.0f / (1.0f + expf(-z));
        out[h * TOT + R0 + row] = o;
    }
}

extern "C" void kernel_launch(void* const* d_in, const int* in_sizes, int n_in,
                              void* d_out, int out_size, void* d_ws, size_t ws_size,
                              hipStream_t stream) {
    const float* x   = (const float*)d_in[0];
    const int*   ei  = (const int*)d_in[1];
    const int*   src = ei;
    const int*   dst = ei + NE;
    const float* W1 = (const float*)d_in[3];
    const float* b1 = (const float*)d_in[4];
    const float* W2 = (const float*)d_in[5];
    const float* b2 = (const float*)d_in[6];
    const float* W3 = (const float*)d_in[7];
    const float* b3 = (const float*)d_in[8];
    const float* tW1 = (const float*)d_in[9];
    const float* tb1 = (const float*)d_in[10];
    const float* tW2 = (const float*)d_in[11];
    const float* tb2 = (const float*)d_in[12];
    const float* tW3 = (const float*)d_in[13];
    const float* tb3 = (const float*)d_in[14];
    const float* Wpi = (const float*)d_in[15];
    const float* bpi = (const float*)d_in[16];
    const float* Wn  = (const float*)d_in[17];
    const float* bn  = (const float*)d_in[18];
    const float* Wp  = (const float*)d_in[19];
    const float* bp  = (const float*)d_in[20];

    // ---- workspace layout ----
    char* ws = (char*)d_ws;
    float* dinv = (float*)(ws + (0ull << 20));            // 512 KB
    int*   gcur = (int*)  (ws + (1ull << 20));            // 64 KB (line-padded)
    int2*  rse  = (int2*) (ws + (1ull << 20) + (256 << 10)); // 1 MB
    unsigned short* wpG1 = (unsigned short*)(ws + (3ull << 20));
    unsigned short* wpG2 = (unsigned short*)(ws + (3ull << 20) + (128 << 10));
    unsigned short* wpG3 = (unsigned short*)(ws + (3ull << 20) + (256 << 10));
    unsigned short* wpC1 = (unsigned short*)(ws + (3ull << 20) + (384 << 10));
    unsigned short* wpC2 = (unsigned short*)(ws + (3ull << 20) + (512 << 10));
    unsigned short* wpC3 = (unsigned short*)(ws + (3ull << 20) + (640 << 10));
    unsigned* buf = (unsigned*)(ws + (4ull << 20));       // 8 MB
    int* adj = (int*)(ws + (12ull << 20));                // 8 MB
    unsigned short* Xa = (unsigned short*)(ws + (24ull  << 20));  // 64ch  16.8 MB
    unsigned short* Xb = (unsigned short*)(ws + (44ull  << 20));  // 128ch 33.6 MB
    unsigned short* Xc = (unsigned short*)(ws + (80ull  << 20));  // 128ch 33.6 MB
    unsigned short* Xd = (unsigned short*)(ws + (116ull << 20));  // 32ch   8.4 MB
    unsigned short* Xe = (unsigned short*)(ws + (128ull << 20));  // 32ch   8.4 MB

    // ---- prep ----
    hipMemsetAsync(gcur, 0, NB * 32 * sizeof(int), stream);
    k_packall<<<352, 256, 0, stream>>>(W1, W2, W3, tW1, tW2, tW3,
                                       wpG1, wpG2, wpG3, wpC1, wpC2, wpC3);

    // ---- adjacency: bucket partition + per-bucket CSR (+ dinv + x-scaling) ----
    k_part<<<NE / EPB, 256, 0, stream>>>(src, dst, gcur, buf);
    k_bcsr<<<NB, 256, 0, stream>>>(buf, gcur, adj, rse, dinv, (const float4*)x, (uint4*)Xa);

    // ---- GCN layer 1: fused gather+GEMM -> h1 ----
    k_gmm<64, true><<<TOT / 64, 256, 0, stream>>>((const uint4*)Xa, adj, rse, dinv,
                                                  (const bf16x8*)wpG1, b1, Xc);

    // ---- GCN layer 2: zs2 = (h1@W2)*dinv; zs3 = relu(agg*dinv + b2)*dinv ----
    k_mm<128, 32, true><<<TOT / 64, 256, 0, stream>>>(Xc, (const bf16x8*)wpG2, dinv, Xd);
    k_gcsr<2><<<TOT * 4 / 256, 256, 0, stream>>>((const uint4*)Xd, adj, rse, dinv,
                                                 b2, (uint4*)Xe);

    // ---- GCN layer 3: fused gather+GEMM -> h3 ----
    k_gmm<32, true><<<TOT / 64, 256, 0, stream>>>((const uint4*)Xe, adj, rse, dinv,
                                                  (const bf16x8*)wpG3, b3, Xb);

    // ---- temporal conv1+conv2+conv3+heads, fully fused in LDS ----
    k_tconv_heads<<<TOT / 64, 256, 0, stream>>>(Xb,
                                                (const bf16x8*)wpC1, tb1,
                                                (const bf16x8*)wpC2, tb2,
                                                (const bf16x8*)wpC3, tb3,
                                                Wpi, bpi, Wn, bn, Wp, bp, (float*)d_out);
}

// Round 10
// 287.338 us; speedup vs baseline: 1.0025x; 1.0025x over previous
//
#include <hip/hip_runtime.h>
#include <cmath>

// Problem constants (fixed by the reference)
constexpr int TOT = 131072;   // 32 graphs * 4096 nodes
constexpr int NE  = 1048576;  // edges
constexpr int NMASK = 4095;   // N-1, N=4096

// Bucketed adjacency
constexpr int NB   = 512;     // buckets (dst >> 8)
constexpr int DPB  = 256;     // dsts per bucket
constexpr int BCAP = 4096;    // slots per bucket (mean 2048)
constexpr int EPB  = 2048;    // edges per partition block

typedef __attribute__((ext_vector_type(8))) short bf16x8;
typedef __attribute__((ext_vector_type(4))) float f32x4;

// ---- bf16 helpers (RNE) ----
__device__ inline float bf2f(unsigned int u16) {
    union { unsigned int i; float f; } x; x.i = u16 << 16; return x.f;
}
__device__ inline unsigned short f2bf(float f) {
    union { float f; unsigned int i; } x; x.f = f;
    unsigned int r = (x.i + 0x7fffu + ((x.i >> 16) & 1u)) >> 16;
    return (unsigned short)r;
}
__device__ inline void unpack8(uint4 v, float* f) {
    f[0] = bf2f(v.x & 0xffffu); f[1] = bf2f(v.x >> 16);
    f[2] = bf2f(v.y & 0xffffu); f[3] = bf2f(v.y >> 16);
    f[4] = bf2f(v.z & 0xffffu); f[5] = bf2f(v.z >> 16);
    f[6] = bf2f(v.w & 0xffffu); f[7] = bf2f(v.w >> 16);
}
__device__ inline uint4 pack8(const float* f) {
    uint4 v;
    v.x = (unsigned)f2bf(f[0]) | ((unsigned)f2bf(f[1]) << 16);
    v.y = (unsigned)f2bf(f[2]) | ((unsigned)f2bf(f[3]) << 16);
    v.z = (unsigned)f2bf(f[4]) | ((unsigned)f2bf(f[5]) << 16);
    v.w = (unsigned)f2bf(f[6]) | ((unsigned)f2bf(f[7]) << 16);
    return v;
}

// ---- weight packing into MFMA B-fragment order (device helper) ----
// reader: lane reads wp[((kc*NT + nt)*64 + lane)*8 + j] = W[kc*32+(lane>>4)*8+j][nt*16+(lane&15)]
__device__ inline void pack_one(const float* __restrict__ w, unsigned short* __restrict__ wp,
                                int CIN, int COUT, int taps, int idx) {
    int j = idx & 7;
    int L = (idx >> 3) & 63;
    int f = idx >> 9;
    int NT = COUT >> 4;
    int kc = f / NT, nt = f - kc * NT;
    int k = kc * 32 + (L >> 4) * 8 + j;
    int n = nt * 16 + (L & 15);
    float v;
    if (taps == 1) v = w[k * COUT + n];
    else { int t = k / CIN, c = k - t * CIN; v = w[(n * CIN + c) * 3 + t]; }
    wp[idx] = f2bf(v);
}

// ================= edge partition by dst bucket (+ fused weight packing) =================
struct PackArgs {
    const float *W1, *W2, *W3, *tW1, *tW2, *tW3;
    unsigned short *g1, *g2, *g3, *c1, *c2, *c3;
};
__global__ __launch_bounds__(256) void k_part(const int* __restrict__ src,
                                              const int* __restrict__ dst,
                                              int* __restrict__ gcur,
                                              unsigned* __restrict__ buf,
                                              PackArgs pa) {
    __shared__ int hist[NB];
    __shared__ int cbase[NB];
    __shared__ int lcur[NB];
    const int tid = threadIdx.x;
    const int e0 = blockIdx.x * EPB;

    for (int b = tid; b < NB; b += 256) hist[b] = 0;
    __syncthreads();
    for (int i = tid; i < EPB; i += 256)
        atomicAdd(&hist[dst[e0 + i] >> 8], 1);
    __syncthreads();
    for (int b = tid; b < NB; b += 256) {
        int c = hist[b];
        cbase[b] = (c > 0) ? atomicAdd(&gcur[b * 32], c) : 0;
        lcur[b] = 0;
    }
    __syncthreads();
    for (int i = tid; i < EPB; i += 256) {
        int e = e0 + i;
        int d = dst[e];
        int b = d >> 8;
        int p = atomicAdd(&lcur[b], 1);
        buf[b * BCAP + cbase[b] + p] = ((unsigned)src[e] << 8) | (unsigned)(d & 255);
    }
    // fused weight packing (rides in this kernel's shadow; no extra dispatch)
    int gid = blockIdx.x * 256 + tid;
    if      (gid <  8192) pack_one(pa.W1,  pa.g1, 64, 128, 1, gid);
    else if (gid < 12288) pack_one(pa.W2,  pa.g2, 128, 32, 1, gid - 8192);
    else if (gid < 16384) pack_one(pa.W3,  pa.g3, 32, 128, 1, gid - 12288);
    else if (gid < 65536) pack_one(pa.tW1, pa.c1, 128, 128, 3, gid - 16384);
    else if (gid < 77824) pack_one(pa.tW2, pa.c2, 128, 32, 3, gid - 65536);
    else if (gid < 90112) pack_one(pa.tW3, pa.c3, 32, 128, 3, gid - 77824);
}

// ================= per-bucket CSR build + dinv + fused x*dinv scaling =================
__global__ __launch_bounds__(256) void k_bcsr(const unsigned* __restrict__ buf,
                                              const int* __restrict__ gcur,
                                              int* __restrict__ adj,
                                              int2* __restrict__ rse,
                                              float* __restrict__ dinv,
                                              const float4* __restrict__ x,
                                              uint4* __restrict__ xsc) {
    __shared__ int cnt[DPB];
    __shared__ int start[DPB];
    __shared__ int cur[DPB];
    __shared__ int sc[DPB];
    const int b = blockIdx.x;
    const int tid = threadIdx.x;
    cnt[tid] = 0;
    __syncthreads();
    const int n = gcur[b * 32];
    const unsigned* eb = buf + b * BCAP;
    for (int i = tid; i < n; i += 256)
        atomicAdd(&cnt[eb[i] & 255u], 1);
    __syncthreads();
    int v = cnt[tid];
    sc[tid] = v;
    __syncthreads();
    for (int off = 1; off < 256; off <<= 1) {
        int a = sc[tid];
        int p = (tid >= off) ? sc[tid - off] : 0;
        __syncthreads();
        sc[tid] = a + p;
        __syncthreads();
    }
    int st = sc[tid] - v;
    start[tid] = st;
    cur[tid] = 0;
    int d = (b << 8) + tid;
    rse[d] = make_int2(b * BCAP + st, v);
    dinv[d] = rsqrtf((float)v + 1.0f);   // +1 self-loop
    __syncthreads();
    for (int i = tid; i < n; i += 256) {
        unsigned w = eb[i];
        int dl = (int)(w & 255u);
        int p = atomicAdd(&cur[dl], 1);
        adj[b * BCAP + start[dl] + p] = (int)(w >> 8);
    }
    // fused: xs = x * dinv -> bf16 for this bucket's 256 rows
    for (int i = tid; i < DPB * 8; i += 256) {
        int rl = i >> 3;
        int t = (b << 11) + i;                 // global uint4 index (row*8+g)
        float dv = rsqrtf((float)cnt[rl] + 1.0f);
        float4 v0 = x[t * 2], v1 = x[t * 2 + 1];
        float f[8] = { v0.x * dv, v0.y * dv, v0.z * dv, v0.w * dv,
                       v1.x * dv, v1.y * dv, v1.z * dv, v1.w * dv };
        xsc[t] = pack8(f);
    }
}

// ================= standalone CSR gather (layer-2 epilogue) =================
template<int LC>
__global__ __launch_bounds__(256) void k_gcsr(const uint4* __restrict__ xs,
                                              const int* __restrict__ adj,
                                              const int2* __restrict__ rse,
                                              const float* __restrict__ dinv,
                                              const float* __restrict__ bias,
                                              uint4* __restrict__ out) {
    int t = blockIdx.x * 256 + threadIdx.x;   // t < TOT << LC
    int d = t >> LC;
    int g = t & ((1 << LC) - 1);
    float a[8];
    unpack8(xs[t], a);                        // self-loop term
    int2 se = rse[d];
    int e = se.x, end = se.x + se.y;
    for (; e + 4 <= end; e += 4) {
        int s0 = adj[e], s1 = adj[e + 1], s2 = adj[e + 2], s3 = adj[e + 3];
        uint4 v0 = xs[(s0 << LC) + g];
        uint4 v1 = xs[(s1 << LC) + g];
        uint4 v2 = xs[(s2 << LC) + g];
        uint4 v3 = xs[(s3 << LC) + g];
        float f[8];
        unpack8(v0, f);
#pragma unroll
        for (int j = 0; j < 8; ++j) a[j] += f[j];
        unpack8(v1, f);
#pragma unroll
        for (int j = 0; j < 8; ++j) a[j] += f[j];
        unpack8(v2, f);
#pragma unroll
        for (int j = 0; j < 8; ++j) a[j] += f[j];
        unpack8(v3, f);
#pragma unroll
        for (int j = 0; j < 8; ++j) a[j] += f[j];
    }
    for (; e < end; ++e) {
        float f[8];
        unpack8(xs[(adj[e] << LC) + g], f);
#pragma unroll
        for (int j = 0; j < 8; ++j) a[j] += f[j];
    }
    float dv = dinv[d];
#pragma unroll
    for (int j = 0; j < 8; ++j)
        a[j] = fmaxf(fmaf(a[j], dv, bias[g * 8 + j]), 0.0f) * dv;
    out[t] = pack8(a);
}

// ================= fused gather + GEMM (CIN->128, TAPS=1) =================
template<int CIN, bool RELU>
__global__ __launch_bounds__(256) void k_gmm(const uint4* __restrict__ xs,
                                             const int* __restrict__ adj,
                                             const int2* __restrict__ rse,
                                             const float* __restrict__ dinv,
                                             const bf16x8* __restrict__ wp,
                                             const float* __restrict__ bias,
                                             unsigned short* __restrict__ y) {
    constexpr int COUT = 128;
    constexpr int ROWS = 64;
    constexpr int SC = CIN + 8;
    constexpr int NV = CIN / 8;           // uint4s per row
    constexpr int VPT = NV / 4;           // uint4s per thread (4 threads/row)
    constexpr int NK = CIN / 32;
    constexpr int NT = COUT / 16;
    constexpr int WN = 2, WM = 4;
    __shared__ __attribute__((aligned(16))) unsigned short tile[ROWS * SC];

    const int R0 = blockIdx.x * ROWS;
    const int tid = threadIdx.x;

    // ---- gather/stage phase ----
    {
        int r = R0 + (tid >> 2);
        int g = tid & 3;
        const uint4* base = xs + (long)r * NV + g * VPT;
        float a[VPT * 8];
#pragma unroll
        for (int v = 0; v < VPT; ++v) unpack8(base[v], a + v * 8);   // self-loop
        int2 se = rse[r];
        int e = se.x, end = se.x + se.y;
        for (; e + 4 <= end; e += 4) {
            int s0 = adj[e], s1 = adj[e + 1], s2 = adj[e + 2], s3 = adj[e + 3];
            const uint4* p0 = xs + (long)s0 * NV + g * VPT;
            const uint4* p1 = xs + (long)s1 * NV + g * VPT;
            const uint4* p2 = xs + (long)s2 * NV + g * VPT;
            const uint4* p3 = xs + (long)s3 * NV + g * VPT;
            uint4 v0[VPT], v1[VPT], v2[VPT], v3[VPT];
#pragma unroll
            for (int v = 0; v < VPT; ++v) { v0[v] = p0[v]; v1[v] = p1[v]; v2[v] = p2[v]; v3[v] = p3[v]; }
            float f[VPT * 8];
#pragma unroll
            for (int v = 0; v < VPT; ++v) unpack8(v0[v], f + v * 8);
#pragma unroll
            for (int j = 0; j < VPT * 8; ++j) a[j] += f[j];
#pragma unroll
            for (int v = 0; v < VPT; ++v) unpack8(v1[v], f + v * 8);
#pragma unroll
            for (int j = 0; j < VPT * 8; ++j) a[j] += f[j];
#pragma unroll
            for (int v = 0; v < VPT; ++v) unpack8(v2[v], f + v * 8);
#pragma unroll
            for (int j = 0; j < VPT * 8; ++j) a[j] += f[j];
#pragma unroll
            for (int v = 0; v < VPT; ++v) unpack8(v3[v], f + v * 8);
#pragma unroll
            for (int j = 0; j < VPT * 8; ++j) a[j] += f[j];
        }
        for (; e < end; ++e) {
            const uint4* p0 = xs + (long)adj[e] * NV + g * VPT;
            float f[VPT * 8];
#pragma unroll
            for (int v = 0; v < VPT; ++v) unpack8(p0[v], f + v * 8);
#pragma unroll
            for (int j = 0; j < VPT * 8; ++j) a[j] += f[j];
        }
        float dv = dinv[r];
#pragma unroll
        for (int j = 0; j < VPT * 8; ++j) a[j] *= dv;
        uint4* dst4 = (uint4*)(tile + (tid >> 2) * SC + g * VPT * 8);
#pragma unroll
        for (int v = 0; v < VPT; ++v) dst4[v] = pack8(a + v * 8);
    }
    __syncthreads();

    // ---- MFMA phase ----
    const int lane = threadIdx.x & 63;
    const int w = threadIdx.x >> 6;
    const int l16 = lane & 15;
    const int q = lane >> 4;
    const int colbase = w * 32;
    const int nt0 = colbase >> 4;

    f32x4 acc[WM][WN];
#pragma unroll
    for (int wm = 0; wm < WM; ++wm)
#pragma unroll
        for (int nt = 0; nt < WN; ++nt) acc[wm][nt] = (f32x4){0.f, 0.f, 0.f, 0.f};

    const bf16x8* __restrict__ wpl = wp + lane;

#pragma unroll
    for (int kc = 0; kc < NK; ++kc) {
        bf16x8 a[WM];
#pragma unroll
        for (int wm = 0; wm < WM; ++wm)
            a[wm] = *(const bf16x8*)(tile + (wm * 16 + l16) * SC + kc * 32 + q * 8);
        bf16x8 b[WN];
#pragma unroll
        for (int nt = 0; nt < WN; ++nt)
            b[nt] = wpl[(kc * NT + nt0 + nt) * 64];
#pragma unroll
        for (int wm = 0; wm < WM; ++wm)
#pragma unroll
            for (int nt = 0; nt < WN; ++nt)
                acc[wm][nt] = __builtin_amdgcn_mfma_f32_16x16x32_bf16(a[wm], b[nt], acc[wm][nt], 0, 0, 0);
    }

#pragma unroll
    for (int wm = 0; wm < WM; ++wm) {
#pragma unroll
        for (int nt = 0; nt < WN; ++nt) {
            int col = colbase + nt * 16 + l16;
            float bi = bias[col];
#pragma unroll
            for (int r = 0; r < 4; ++r) {
                int row = R0 + wm * 16 + q * 4 + r;
                float v = acc[wm][nt][r] + bi;
                if (RELU) v = fmaxf(v, 0.0f);
                y[(long)row * COUT + col] = f2bf(v);
            }
        }
    }
}

// ================= MFMA dense / conv1d (round-8 proven) =================
template<int CIN, int COUT, int TAPS, bool RELU, bool BIAS, bool SOUT>
__global__ __launch_bounds__(256) void k_mm(const unsigned short* __restrict__ x,
                                            const bf16x8* __restrict__ wp,
                                            const float* __restrict__ bias,
                                            const float* __restrict__ dinv,
                                            unsigned short* __restrict__ y) {
    constexpr int ROWS = 64;
    constexpr int HALO = (TAPS == 3) ? 1 : 0;
    constexpr int TR = ROWS + 2 * HALO;
    constexpr int SC = CIN + 8;
    constexpr int NCH = CIN / 32;
    constexpr int NK = TAPS * NCH;
    constexpr int NT = COUT / 16;
    constexpr int WN = (COUT == 128) ? 2 : 1;
    constexpr int WM = (COUT == 128) ? 4 : 2;
    __shared__ __attribute__((aligned(16))) unsigned short tile[TR * SC];

    const int R0 = blockIdx.x * ROWS;
    const int n0 = R0 & NMASK; (void)n0;

    constexpr int NLD = TR * (CIN / 8);
    for (int idx = threadIdx.x; idx < NLD; idx += 256) {
        int tr = idx / (CIN / 8);
        int c8 = idx - tr * (CIN / 8);
        int ro = tr - HALO;
        bool valid = true;
        if (TAPS == 3) {
            if (ro < 0) valid = (n0 > 0);
            else if (ro >= ROWS) valid = (n0 + ROWS < 4096);
        }
        uint4 v = make_uint4(0, 0, 0, 0);
        if (valid) v = *(const uint4*)(x + (long)(R0 + ro) * CIN + c8 * 8);
        *(uint4*)(tile + tr * SC + c8 * 8) = v;
    }
    __syncthreads();

    const int lane = threadIdx.x & 63;
    const int w = threadIdx.x >> 6;
    const int l16 = lane & 15;
    const int q = lane >> 4;
    const int colbase = (COUT == 128) ? w * 32 : (w & 1) * 16;
    const int rowbase = (COUT == 128) ? 0 : (w >> 1) * 32;
    const int nt0 = colbase >> 4;

    f32x4 acc[WM][WN];
#pragma unroll
    for (int wm = 0; wm < WM; ++wm)
#pragma unroll
        for (int nt = 0; nt < WN; ++nt) acc[wm][nt] = (f32x4){0.f, 0.f, 0.f, 0.f};

    const bf16x8* __restrict__ wpl = wp + lane;

#pragma unroll
    for (int kc = 0; kc < NK; ++kc) {
        const int tap = (TAPS == 3) ? (kc / NCH) : 0;
        const int ch  = (TAPS == 3) ? (kc - tap * NCH) : kc;
        bf16x8 a[WM];
#pragma unroll
        for (int wm = 0; wm < WM; ++wm)
            a[wm] = *(const bf16x8*)(tile + (rowbase + wm * 16 + l16 + tap) * SC + ch * 32 + q * 8);
        bf16x8 b[WN];
#pragma unroll
        for (int nt = 0; nt < WN; ++nt)
            b[nt] = wpl[(kc * NT + nt0 + nt) * 64];
#pragma unroll
        for (int wm = 0; wm < WM; ++wm)
#pragma unroll
            for (int nt = 0; nt < WN; ++nt)
                acc[wm][nt] = __builtin_amdgcn_mfma_f32_16x16x32_bf16(a[wm], b[nt], acc[wm][nt], 0, 0, 0);
    }

    // epilogue: C/D layout col=lane&15, row=q*4+reg
#pragma unroll
    for (int wm = 0; wm < WM; ++wm) {
#pragma unroll
        for (int nt = 0; nt < WN; ++nt) {
            int col = colbase + nt * 16 + l16;
            float bi = BIAS ? bias[col] : 0.0f;
#pragma unroll
            for (int r = 0; r < 4; ++r) {
                int row = R0 + rowbase + wm * 16 + q * 4 + r;
                float v = acc[wm][nt][r] + bi;
                if (RELU) v = fmaxf(v, 0.0f);
                if (SOUT) v *= dinv[row];
                y[(long)row * COUT + col] = f2bf(v);
            }
        }
    }
}

// ================= fused conv2 (128->32) + conv3 (32->128) + heads =================
// Stage 82 rows of conv1's output (c1) -> conv2 -> c2(66x40) -> conv3 -> xts
// (aliases c1) -> heads. 27.6 KB LDS -> 5 blocks/CU (round-9's 49 KB monster
// split: conv1 stays standalone).
__global__ __launch_bounds__(256) void k_c23_heads(
    const unsigned short* __restrict__ x,      // conv1 output [TOT,128] bf16
    const bf16x8* __restrict__ wp2, const float* __restrict__ tb2,
    const bf16x8* __restrict__ wp3, const float* __restrict__ tb3,
    const float* __restrict__ Wpi, const float* __restrict__ bpi,
    const float* __restrict__ Wn,  const float* __restrict__ bn,
    const float* __restrict__ Wp,  const float* __restrict__ bp,
    float* __restrict__ out) {
    constexpr int SC1 = 136;
    constexpr int SC2 = 40;
    __shared__ __attribute__((aligned(16))) unsigned short shl[82 * 136 + 66 * 40];
    unsigned short* c1  = shl;                // 82 rows: global [R0-2, R0+80)
    unsigned short* c2  = shl + 82 * 136;     // 66 rows: global [R0-1, R0+65)
    unsigned short* xts = shl;                // alias (c1 dead after conv2)

    const int R0 = blockIdx.x * 64;
    const int n0 = R0 & NMASK;
    const int tid = threadIdx.x;

    // ---- stage c1 (zero outside batch) ----
    for (int i = tid; i < 82 * 16; i += 256) {
        int r = i >> 4;
        int c8 = i & 15;
        int n = n0 - 2 + r;
        uint4 v = make_uint4(0, 0, 0, 0);
        if (n >= 0 && n < 4096)
            v = *(const uint4*)(x + (long)(R0 - 2 + r) * 128 + c8 * 8);
        *(uint4*)(c1 + r * SC1 + c8 * 8) = v;
    }
    __syncthreads();

    const int lane = tid & 63;
    const int w = tid >> 6;
    const int l16 = lane & 15;
    const int q = lane >> 4;

    // ---- conv2: 128->32, 5 row-tiles at [R0-1 + 16rt), wave rts {w, w+4} ----
    for (int rt = w; rt < 5; rt += 4) {
        f32x4 acc[2];
#pragma unroll
        for (int nt = 0; nt < 2; ++nt) acc[nt] = (f32x4){0.f, 0.f, 0.f, 0.f};
        const bf16x8* wpl = wp2 + lane;
#pragma unroll
        for (int kc = 0; kc < 12; ++kc) {
            int tap = kc >> 2, ch = kc & 3;
            bf16x8 a = *(const bf16x8*)(c1 + (16 * rt + l16 + tap) * SC1 + ch * 32 + q * 8);
            bf16x8 b0 = wpl[(kc * 2 + 0) * 64];
            bf16x8 b1 = wpl[(kc * 2 + 1) * 64];
            acc[0] = __builtin_amdgcn_mfma_f32_16x16x32_bf16(a, b0, acc[0], 0, 0, 0);
            acc[1] = __builtin_amdgcn_mfma_f32_16x16x32_bf16(a, b1, acc[1], 0, 0, 0);
        }
#pragma unroll
        for (int nt = 0; nt < 2; ++nt) {
            int col = nt * 16 + l16;
            float bi = tb2[col];
#pragma unroll
            for (int r = 0; r < 4; ++r) {
                int idx = 16 * rt + q * 4 + r;              // c2 row index
                if (idx < 66) {
                    int n = n0 - 1 + idx;
                    unsigned short v = 0;
                    if (n >= 0 && n < 4096)
                        v = f2bf(fmaxf(acc[nt][r] + bi, 0.0f));
                    c2[idx * SC2 + col] = v;
                }
            }
        }
    }
    __syncthreads();   // conv2 done: c1 dead, c2 ready

    // ---- conv3: 32->128, 4 row-tiles at R0, wave cols {2w,2w+1}; write xts ----
    {
        f32x4 acc[4][2];
#pragma unroll
        for (int rt = 0; rt < 4; ++rt)
#pragma unroll
            for (int nt = 0; nt < 2; ++nt) acc[rt][nt] = (f32x4){0.f, 0.f, 0.f, 0.f};
        const bf16x8* wpl = wp3 + lane;
#pragma unroll
        for (int kc = 0; kc < 3; ++kc) {
            bf16x8 a[4];
#pragma unroll
            for (int rt = 0; rt < 4; ++rt)
                a[rt] = *(const bf16x8*)(c2 + (16 * rt + l16 + kc) * SC2 + q * 8);
            bf16x8 b[2];
#pragma unroll
            for (int nt = 0; nt < 2; ++nt)
                b[nt] = wpl[(kc * 8 + 2 * w + nt) * 64];
#pragma unroll
            for (int rt = 0; rt < 4; ++rt)
#pragma unroll
                for (int nt = 0; nt < 2; ++nt)
                    acc[rt][nt] = __builtin_amdgcn_mfma_f32_16x16x32_bf16(a[rt], b[nt], acc[rt][nt], 0, 0, 0);
        }
#pragma unroll
        for (int rt = 0; rt < 4; ++rt) {
#pragma unroll
            for (int nt = 0; nt < 2; ++nt) {
                int col = w * 32 + nt * 16 + l16;
                float bi = tb3[col];
#pragma unroll
                for (int r = 0; r < 4; ++r) {
                    int row = 16 * rt + q * 4 + r;
                    xts[row * 130 + col] = f2bf(fmaxf(acc[rt][nt][r] + bi, 0.0f));
                }
            }
        }
    }
    __syncthreads();

    // ---- heads ----
    if (tid < 192) {
        int h = tid >> 6;                      // wave-uniform
        int row = tid & 63;
        const float* Wh = (h == 0) ? Wpi : (h == 1) ? Wn : Wp;
        float s = 0.0f;
        const unsigned short* xr = xts + row * 130;
#pragma unroll
        for (int c2i = 0; c2i < 64; ++c2i) {
            unsigned u = *(const unsigned*)(xr + c2i * 2);
            s = fmaf(bf2f(u & 0xffffu), Wh[c2i * 2], s);
            s = fmaf(bf2f(u >> 16), Wh[c2i * 2 + 1], s);
        }
        float bb = (h == 0) ? bpi[0] : (h == 1) ? bn[0] : bp[0];
        float z = s + bb;
        float o;
        if (h == 1) o = (z > 20.0f) ? z : log1pf(expf(z));
        else        o = 1.0f / (1.0f + expf(-z));
        out[h * TOT + R0 + row] = o;
    }
}

extern "C" void kernel_launch(void* const* d_in, const int* in_sizes, int n_in,
                              void* d_out, int out_size, void* d_ws, size_t ws_size,
                              hipStream_t stream) {
    const float* x   = (const float*)d_in[0];
    const int*   ei  = (const int*)d_in[1];
    const int*   src = ei;
    const int*   dst = ei + NE;
    const float* W1 = (const float*)d_in[3];
    const float* b1 = (const float*)d_in[4];
    const float* W2 = (const float*)d_in[5];
    const float* b2 = (const float*)d_in[6];
    const float* W3 = (const float*)d_in[7];
    const float* b3 = (const float*)d_in[8];
    const float* tW1 = (const float*)d_in[9];
    const float* tb1 = (const float*)d_in[10];
    const float* tW2 = (const float*)d_in[11];
    const float* tb2 = (const float*)d_in[12];
    const float* tW3 = (const float*)d_in[13];
    const float* tb3 = (const float*)d_in[14];
    const float* Wpi = (const float*)d_in[15];
    const float* bpi = (const float*)d_in[16];
    const float* Wn  = (const float*)d_in[17];
    const float* bn  = (const float*)d_in[18];
    const float* Wp  = (const float*)d_in[19];
    const float* bp  = (const float*)d_in[20];

    // ---- workspace layout ----
    char* ws = (char*)d_ws;
    float* dinv = (float*)(ws + (0ull << 20));            // 512 KB
    int*   gcur = (int*)  (ws + (1ull << 20));            // 64 KB (line-padded)
    int2*  rse  = (int2*) (ws + (1ull << 20) + (256 << 10)); // 1 MB
    unsigned short* wpG1 = (unsigned short*)(ws + (3ull << 20));
    unsigned short* wpG2 = (unsigned short*)(ws + (3ull << 20) + (128 << 10));
    unsigned short* wpG3 = (unsigned short*)(ws + (3ull << 20) + (256 << 10));
    unsigned short* wpC1 = (unsigned short*)(ws + (3ull << 20) + (384 << 10));
    unsigned short* wpC2 = (unsigned short*)(ws + (3ull << 20) + (512 << 10));
    unsigned short* wpC3 = (unsigned short*)(ws + (3ull << 20) + (640 << 10));
    unsigned* buf = (unsigned*)(ws + (4ull << 20));       // 8 MB
    int* adj = (int*)(ws + (12ull << 20));                // 8 MB
    unsigned short* Xa = (unsigned short*)(ws + (24ull  << 20));  // 64ch  16.8 MB
    unsigned short* Xb = (unsigned short*)(ws + (44ull  << 20));  // 128ch 33.6 MB
    unsigned short* Xc = (unsigned short*)(ws + (80ull  << 20));  // 128ch 33.6 MB
    unsigned short* Xd = (unsigned short*)(ws + (116ull << 20));  // 32ch   8.4 MB
    unsigned short* Xe = (unsigned short*)(ws + (128ull << 20));  // 32ch   8.4 MB

    // ---- prep ----
    hipMemsetAsync(gcur, 0, NB * 32 * sizeof(int), stream);

    // ---- adjacency: bucket partition (+ fused weight packing) + per-bucket CSR ----
    PackArgs pa = { W1, W2, W3, tW1, tW2, tW3, wpG1, wpG2, wpG3, wpC1, wpC2, wpC3 };
    k_part<<<NE / EPB, 256, 0, stream>>>(src, dst, gcur, buf, pa);
    k_bcsr<<<NB, 256, 0, stream>>>(buf, gcur, adj, rse, dinv, (const float4*)x, (uint4*)Xa);

    // ---- GCN layer 1: fused gather+GEMM -> h1 ----
    k_gmm<64, true><<<TOT / 64, 256, 0, stream>>>((const uint4*)Xa, adj, rse, dinv,
                                                  (const bf16x8*)wpG1, b1, Xc);

    // ---- GCN layer 2: zs2 = (h1@W2)*dinv; zs3 = relu(agg*dinv + b2)*dinv ----
    k_mm<128, 32, 1, false, false, true>
        <<<TOT / 64, 256, 0, stream>>>(Xc, (const bf16x8*)wpG2, nullptr, dinv, Xd);
    k_gcsr<2><<<TOT * 4 / 256, 256, 0, stream>>>((const uint4*)Xd, adj, rse, dinv,
                                                 b2, (uint4*)Xe);

    // ---- GCN layer 3: fused gather+GEMM -> h3 ----
    k_gmm<32, true><<<TOT / 64, 256, 0, stream>>>((const uint4*)Xe, adj, rse, dinv,
                                                  (const bf16x8*)wpG3, b3, Xb);

    // ---- temporal conv1 (standalone, proven) ----
    k_mm<128, 128, 3, true, true, false>
        <<<TOT / 64, 256, 0, stream>>>(Xb, (const bf16x8*)wpC1, tb1, nullptr, Xc);

    // ---- conv2 + conv3 + heads fused ----
    k_c23_heads<<<TOT / 64, 256, 0, stream>>>(Xc,
                                              (const bf16x8*)wpC2, tb2,
                                              (const bf16x8*)wpC3, tb3,
                                              Wpi, bpi, Wn, bn, Wp, bp, (float*)d_out);
}

// Round 11
// 276.744 us; speedup vs baseline: 1.0408x; 1.0383x over previous
//
#include <hip/hip_runtime.h>
#include <cmath>

// Problem constants (fixed by the reference)
constexpr int TOT = 131072;   // 32 graphs * 4096 nodes
constexpr int NE  = 1048576;  // edges
constexpr int NMASK = 4095;   // N-1, N=4096

// Bucketed adjacency
constexpr int NB   = 512;     // buckets (dst >> 8)
constexpr int DPB  = 256;     // dsts per bucket
constexpr int BCAP = 4096;    // slots per bucket (mean 2048)
constexpr int EPB  = 2048;    // edges per partition block

typedef __attribute__((ext_vector_type(8))) short bf16x8;
typedef __attribute__((ext_vector_type(4))) float f32x4;

// ---- bf16 helpers (RNE) ----
__device__ inline float bf2f(unsigned int u16) {
    union { unsigned int i; float f; } x; x.i = u16 << 16; return x.f;
}
__device__ inline unsigned short f2bf(float f) {
    union { float f; unsigned int i; } x; x.f = f;
    unsigned int r = (x.i + 0x7fffu + ((x.i >> 16) & 1u)) >> 16;
    return (unsigned short)r;
}
__device__ inline void unpack8(uint4 v, float* f) {
    f[0] = bf2f(v.x & 0xffffu); f[1] = bf2f(v.x >> 16);
    f[2] = bf2f(v.y & 0xffffu); f[3] = bf2f(v.y >> 16);
    f[4] = bf2f(v.z & 0xffffu); f[5] = bf2f(v.z >> 16);
    f[6] = bf2f(v.w & 0xffffu); f[7] = bf2f(v.w >> 16);
}
__device__ inline uint4 pack8(const float* f) {
    uint4 v;
    v.x = (unsigned)f2bf(f[0]) | ((unsigned)f2bf(f[1]) << 16);
    v.y = (unsigned)f2bf(f[2]) | ((unsigned)f2bf(f[3]) << 16);
    v.z = (unsigned)f2bf(f[4]) | ((unsigned)f2bf(f[5]) << 16);
    v.w = (unsigned)f2bf(f[6]) | ((unsigned)f2bf(f[7]) << 16);
    return v;
}

// ---- weight packing into MFMA B-fragment order (device helper) ----
__device__ inline void pack_one(const float* __restrict__ w, unsigned short* __restrict__ wp,
                                int CIN, int COUT, int taps, int idx) {
    int j = idx & 7;
    int L = (idx >> 3) & 63;
    int f = idx >> 9;
    int NT = COUT >> 4;
    int kc = f / NT, nt = f - kc * NT;
    int k = kc * 32 + (L >> 4) * 8 + j;
    int n = nt * 16 + (L & 15);
    float v;
    if (taps == 1) v = w[k * COUT + n];
    else { int t = k / CIN, c = k - t * CIN; v = w[(n * CIN + c) * 3 + t]; }
    wp[idx] = f2bf(v);
}

// ================= edge partition by dst bucket (+ fused weight packing) =================
struct PackArgs {
    const float *W1, *W2, *W3, *tW1, *tW2, *tW3;
    unsigned short *g1, *g2, *g3, *c1, *c2, *c3;
};
__global__ __launch_bounds__(256) void k_part(const int* __restrict__ src,
                                              const int* __restrict__ dst,
                                              int* __restrict__ gcur,
                                              unsigned* __restrict__ buf,
                                              PackArgs pa) {
    __shared__ int hist[NB];
    __shared__ int cbase[NB];
    __shared__ int lcur[NB];
    const int tid = threadIdx.x;
    const int e0 = blockIdx.x * EPB;

    for (int b = tid; b < NB; b += 256) hist[b] = 0;
    __syncthreads();
    for (int i = tid; i < EPB; i += 256)
        atomicAdd(&hist[dst[e0 + i] >> 8], 1);
    __syncthreads();
    for (int b = tid; b < NB; b += 256) {
        int c = hist[b];
        cbase[b] = (c > 0) ? atomicAdd(&gcur[b * 32], c) : 0;
        lcur[b] = 0;
    }
    __syncthreads();
    for (int i = tid; i < EPB; i += 256) {
        int e = e0 + i;
        int d = dst[e];
        int b = d >> 8;
        int p = atomicAdd(&lcur[b], 1);
        buf[b * BCAP + cbase[b] + p] = ((unsigned)src[e] << 8) | (unsigned)(d & 255);
    }
    // fused weight packing
    int gid = blockIdx.x * 256 + tid;
    if      (gid <  8192) pack_one(pa.W1,  pa.g1, 64, 128, 1, gid);
    else if (gid < 12288) pack_one(pa.W2,  pa.g2, 128, 32, 1, gid - 8192);
    else if (gid < 16384) pack_one(pa.W3,  pa.g3, 32, 128, 1, gid - 12288);
    else if (gid < 65536) pack_one(pa.tW1, pa.c1, 128, 128, 3, gid - 16384);
    else if (gid < 77824) pack_one(pa.tW2, pa.c2, 128, 32, 3, gid - 65536);
    else if (gid < 90112) pack_one(pa.tW3, pa.c3, 32, 128, 3, gid - 77824);
}

// ================= per-bucket CSR build + dinv + fused x*dinv scaling =================
__global__ __launch_bounds__(256) void k_bcsr(const unsigned* __restrict__ buf,
                                              const int* __restrict__ gcur,
                                              int* __restrict__ adj,
                                              int2* __restrict__ rse,
                                              float* __restrict__ dinv,
                                              const float4* __restrict__ x,
                                              uint4* __restrict__ xsc) {
    __shared__ int cnt[DPB];
    __shared__ int start[DPB];
    __shared__ int cur[DPB];
    __shared__ int sc[DPB];
    const int b = blockIdx.x;
    const int tid = threadIdx.x;
    cnt[tid] = 0;
    __syncthreads();
    const int n = gcur[b * 32];
    const unsigned* eb = buf + b * BCAP;
    for (int i = tid; i < n; i += 256)
        atomicAdd(&cnt[eb[i] & 255u], 1);
    __syncthreads();
    int v = cnt[tid];
    sc[tid] = v;
    __syncthreads();
    for (int off = 1; off < 256; off <<= 1) {
        int a = sc[tid];
        int p = (tid >= off) ? sc[tid - off] : 0;
        __syncthreads();
        sc[tid] = a + p;
        __syncthreads();
    }
    int st = sc[tid] - v;
    start[tid] = st;
    cur[tid] = 0;
    int d = (b << 8) + tid;
    rse[d] = make_int2(b * BCAP + st, v);
    dinv[d] = rsqrtf((float)v + 1.0f);   // +1 self-loop
    __syncthreads();
    for (int i = tid; i < n; i += 256) {
        unsigned w = eb[i];
        int dl = (int)(w & 255u);
        int p = atomicAdd(&cur[dl], 1);
        adj[b * BCAP + start[dl] + p] = (int)(w >> 8);
    }
    // fused: xs = x * dinv -> bf16 for this bucket's 256 rows
    for (int i = tid; i < DPB * 8; i += 256) {
        int rl = i >> 3;
        int t = (b << 11) + i;                 // global uint4 index (row*8+g)
        float dv = rsqrtf((float)cnt[rl] + 1.0f);
        float4 v0 = x[t * 2], v1 = x[t * 2 + 1];
        float f[8] = { v0.x * dv, v0.y * dv, v0.z * dv, v0.w * dv,
                       v1.x * dv, v1.y * dv, v1.z * dv, v1.w * dv };
        xsc[t] = pack8(f);
    }
}

// ================= standalone CSR gather (layer-2 epilogue) =================
template<int LC>
__global__ __launch_bounds__(256) void k_gcsr(const uint4* __restrict__ xs,
                                              const int* __restrict__ adj,
                                              const int2* __restrict__ rse,
                                              const float* __restrict__ dinv,
                                              const float* __restrict__ bias,
                                              uint4* __restrict__ out) {
    int t = blockIdx.x * 256 + threadIdx.x;   // t < TOT << LC
    int d = t >> LC;
    int g = t & ((1 << LC) - 1);
    float a[8];
    unpack8(xs[t], a);                        // self-loop term
    int2 se = rse[d];
    int e = se.x, end = se.x + se.y;
    for (; e + 4 <= end; e += 4) {
        int s0 = adj[e], s1 = adj[e + 1], s2 = adj[e + 2], s3 = adj[e + 3];
        uint4 v0 = xs[(s0 << LC) + g];
        uint4 v1 = xs[(s1 << LC) + g];
        uint4 v2 = xs[(s2 << LC) + g];
        uint4 v3 = xs[(s3 << LC) + g];
        float f[8];
        unpack8(v0, f);
#pragma unroll
        for (int j = 0; j < 8; ++j) a[j] += f[j];
        unpack8(v1, f);
#pragma unroll
        for (int j = 0; j < 8; ++j) a[j] += f[j];
        unpack8(v2, f);
#pragma unroll
        for (int j = 0; j < 8; ++j) a[j] += f[j];
        unpack8(v3, f);
#pragma unroll
        for (int j = 0; j < 8; ++j) a[j] += f[j];
    }
    for (; e < end; ++e) {
        float f[8];
        unpack8(xs[(adj[e] << LC) + g], f);
#pragma unroll
        for (int j = 0; j < 8; ++j) a[j] += f[j];
    }
    float dv = dinv[d];
#pragma unroll
    for (int j = 0; j < 8; ++j)
        a[j] = fmaxf(fmaf(a[j], dv, bias[g * 8 + j]), 0.0f) * dv;
    out[t] = pack8(a);
}

// ================= fused gather + GEMM1 (64->128) + GEMM2 (128->32) =================
// Layer-1 gather stages agg into tile1; GEMM1 computes h1 = relu(agg@W1+b1)
// whose epilogue writes an LDS tile (stride 144: word-stride 72 -> scalar b16
// writes land 2 lanes/bank = free, b128 reads 8 words/bank = minimum);
// GEMM2 then computes zs2 = (h1@W2)*dinv directly. h1 (33.6 MB) never
// touches HBM, and the k_mm<128,32> dispatch disappears.
__global__ __launch_bounds__(256) void k_gmm2(const uint4* __restrict__ xs,
                                              const int* __restrict__ adj,
                                              const int2* __restrict__ rse,
                                              const float* __restrict__ dinv,
                                              const bf16x8* __restrict__ wp1,
                                              const float* __restrict__ b1,
                                              const bf16x8* __restrict__ wp2,
                                              unsigned short* __restrict__ y) {
    constexpr int CIN = 64;
    constexpr int ROWS = 64;
    constexpr int SC  = CIN + 8;          // 72: gather tile stride
    constexpr int SCH = 144;              // h1 tile stride (conflict-free both ways)
    constexpr int NV = CIN / 8;           // 8 uint4s per row
    constexpr int VPT = NV / 4;           // 2 uint4s per thread (4 threads/row)
    __shared__ __attribute__((aligned(16))) unsigned short tile1[ROWS * SC];
    __shared__ __attribute__((aligned(16))) unsigned short h1t[ROWS * SCH];

    const int R0 = blockIdx.x * ROWS;
    const int tid = threadIdx.x;

    // ---- gather/stage phase ----
    {
        int r = R0 + (tid >> 2);
        int g = tid & 3;
        const uint4* base = xs + (long)r * NV + g * VPT;
        float a[VPT * 8];
#pragma unroll
        for (int v = 0; v < VPT; ++v) unpack8(base[v], a + v * 8);   // self-loop
        int2 se = rse[r];
        int e = se.x, end = se.x + se.y;
        for (; e + 4 <= end; e += 4) {
            int s0 = adj[e], s1 = adj[e + 1], s2 = adj[e + 2], s3 = adj[e + 3];
            const uint4* p0 = xs + (long)s0 * NV + g * VPT;
            const uint4* p1 = xs + (long)s1 * NV + g * VPT;
            const uint4* p2 = xs + (long)s2 * NV + g * VPT;
            const uint4* p3 = xs + (long)s3 * NV + g * VPT;
            uint4 v0[VPT], v1[VPT], v2[VPT], v3[VPT];
#pragma unroll
            for (int v = 0; v < VPT; ++v) { v0[v] = p0[v]; v1[v] = p1[v]; v2[v] = p2[v]; v3[v] = p3[v]; }
            float f[VPT * 8];
#pragma unroll
            for (int v = 0; v < VPT; ++v) unpack8(v0[v], f + v * 8);
#pragma unroll
            for (int j = 0; j < VPT * 8; ++j) a[j] += f[j];
#pragma unroll
            for (int v = 0; v < VPT; ++v) unpack8(v1[v], f + v * 8);
#pragma unroll
            for (int j = 0; j < VPT * 8; ++j) a[j] += f[j];
#pragma unroll
            for (int v = 0; v < VPT; ++v) unpack8(v2[v], f + v * 8);
#pragma unroll
            for (int j = 0; j < VPT * 8; ++j) a[j] += f[j];
#pragma unroll
            for (int v = 0; v < VPT; ++v) unpack8(v3[v], f + v * 8);
#pragma unroll
            for (int j = 0; j < VPT * 8; ++j) a[j] += f[j];
        }
        for (; e < end; ++e) {
            const uint4* p0 = xs + (long)adj[e] * NV + g * VPT;
            float f[VPT * 8];
#pragma unroll
            for (int v = 0; v < VPT; ++v) unpack8(p0[v], f + v * 8);
#pragma unroll
            for (int j = 0; j < VPT * 8; ++j) a[j] += f[j];
        }
        float dv = dinv[r];
#pragma unroll
        for (int j = 0; j < VPT * 8; ++j) a[j] *= dv;
        uint4* dst4 = (uint4*)(tile1 + (tid >> 2) * SC + g * VPT * 8);
#pragma unroll
        for (int v = 0; v < VPT; ++v) dst4[v] = pack8(a + v * 8);
    }
    __syncthreads();

    const int lane = tid & 63;
    const int w = tid >> 6;
    const int l16 = lane & 15;
    const int q = lane >> 4;

    // ---- GEMM1: 64 -> 128, wave w = cols [32w, 32w+32) ----
    {
        f32x4 acc[4][2];
#pragma unroll
        for (int wm = 0; wm < 4; ++wm)
#pragma unroll
            for (int nt = 0; nt < 2; ++nt) acc[wm][nt] = (f32x4){0.f, 0.f, 0.f, 0.f};
        const bf16x8* wpl = wp1 + lane;
        const int nt0 = w * 2;
#pragma unroll
        for (int kc = 0; kc < 2; ++kc) {
            bf16x8 a[4];
#pragma unroll
            for (int wm = 0; wm < 4; ++wm)
                a[wm] = *(const bf16x8*)(tile1 + (wm * 16 + l16) * SC + kc * 32 + q * 8);
            bf16x8 b[2];
#pragma unroll
            for (int nt = 0; nt < 2; ++nt)
                b[nt] = wpl[(kc * 8 + nt0 + nt) * 64];
#pragma unroll
            for (int wm = 0; wm < 4; ++wm)
#pragma unroll
                for (int nt = 0; nt < 2; ++nt)
                    acc[wm][nt] = __builtin_amdgcn_mfma_f32_16x16x32_bf16(a[wm], b[nt], acc[wm][nt], 0, 0, 0);
        }
        // epilogue 1 -> h1 LDS tile (relu + bias, bf16 round)
#pragma unroll
        for (int wm = 0; wm < 4; ++wm) {
#pragma unroll
            for (int nt = 0; nt < 2; ++nt) {
                int col = w * 32 + nt * 16 + l16;
                float bi = b1[col];
#pragma unroll
                for (int r = 0; r < 4; ++r) {
                    int row = wm * 16 + q * 4 + r;
                    h1t[row * SCH + col] = f2bf(fmaxf(acc[wm][nt][r] + bi, 0.0f));
                }
            }
        }
    }
    __syncthreads();

    // ---- GEMM2: 128 -> 32, wave: cols (w&1)*16, rows (w>>1)*32 ----
    {
        const int colbase = (w & 1) * 16;
        const int rowbase = (w >> 1) * 32;
        const int nt0 = colbase >> 4;
        f32x4 acc[2];
#pragma unroll
        for (int wm = 0; wm < 2; ++wm) acc[wm] = (f32x4){0.f, 0.f, 0.f, 0.f};
        const bf16x8* wpl = wp2 + lane;
#pragma unroll
        for (int kc = 0; kc < 4; ++kc) {
            bf16x8 a[2];
#pragma unroll
            for (int wm = 0; wm < 2; ++wm)
                a[wm] = *(const bf16x8*)(h1t + (rowbase + wm * 16 + l16) * SCH + kc * 32 + q * 8);
            bf16x8 b = wpl[(kc * 2 + nt0) * 64];
#pragma unroll
            for (int wm = 0; wm < 2; ++wm)
                acc[wm] = __builtin_amdgcn_mfma_f32_16x16x32_bf16(a[wm], b, acc[wm], 0, 0, 0);
        }
#pragma unroll
        for (int wm = 0; wm < 2; ++wm) {
            int col = colbase + l16;
#pragma unroll
            for (int r = 0; r < 4; ++r) {
                int row = R0 + rowbase + wm * 16 + q * 4 + r;
                float v = acc[wm][r] * dinv[row];
                y[(long)row * 32 + col] = f2bf(v);
            }
        }
    }
}

// ================= fused gather + GEMM (CIN->128, layer 3) =================
template<int CIN, bool RELU>
__global__ __launch_bounds__(256) void k_gmm(const uint4* __restrict__ xs,
                                             const int* __restrict__ adj,
                                             const int2* __restrict__ rse,
                                             const float* __restrict__ dinv,
                                             const bf16x8* __restrict__ wp,
                                             const float* __restrict__ bias,
                                             unsigned short* __restrict__ y) {
    constexpr int COUT = 128;
    constexpr int ROWS = 64;
    constexpr int SC = CIN + 8;
    constexpr int NV = CIN / 8;
    constexpr int VPT = NV / 4;
    constexpr int NK = CIN / 32;
    constexpr int NT = COUT / 16;
    constexpr int WN = 2, WM = 4;
    __shared__ __attribute__((aligned(16))) unsigned short tile[ROWS * SC];

    const int R0 = blockIdx.x * ROWS;
    const int tid = threadIdx.x;

    {
        int r = R0 + (tid >> 2);
        int g = tid & 3;
        const uint4* base = xs + (long)r * NV + g * VPT;
        float a[VPT * 8];
#pragma unroll
        for (int v = 0; v < VPT; ++v) unpack8(base[v], a + v * 8);
        int2 se = rse[r];
        int e = se.x, end = se.x + se.y;
        for (; e + 4 <= end; e += 4) {
            int s0 = adj[e], s1 = adj[e + 1], s2 = adj[e + 2], s3 = adj[e + 3];
            const uint4* p0 = xs + (long)s0 * NV + g * VPT;
            const uint4* p1 = xs + (long)s1 * NV + g * VPT;
            const uint4* p2 = xs + (long)s2 * NV + g * VPT;
            const uint4* p3 = xs + (long)s3 * NV + g * VPT;
            uint4 v0[VPT], v1[VPT], v2[VPT], v3[VPT];
#pragma unroll
            for (int v = 0; v < VPT; ++v) { v0[v] = p0[v]; v1[v] = p1[v]; v2[v] = p2[v]; v3[v] = p3[v]; }
            float f[VPT * 8];
#pragma unroll
            for (int v = 0; v < VPT; ++v) unpack8(v0[v], f + v * 8);
#pragma unroll
            for (int j = 0; j < VPT * 8; ++j) a[j] += f[j];
#pragma unroll
            for (int v = 0; v < VPT; ++v) unpack8(v1[v], f + v * 8);
#pragma unroll
            for (int j = 0; j < VPT * 8; ++j) a[j] += f[j];
#pragma unroll
            for (int v = 0; v < VPT; ++v) unpack8(v2[v], f + v * 8);
#pragma unroll
            for (int j = 0; j < VPT * 8; ++j) a[j] += f[j];
#pragma unroll
            for (int v = 0; v < VPT; ++v) unpack8(v3[v], f + v * 8);
#pragma unroll
            for (int j = 0; j < VPT * 8; ++j) a[j] += f[j];
        }
        for (; e < end; ++e) {
            const uint4* p0 = xs + (long)adj[e] * NV + g * VPT;
            float f[VPT * 8];
#pragma unroll
            for (int v = 0; v < VPT; ++v) unpack8(p0[v], f + v * 8);
#pragma unroll
            for (int j = 0; j < VPT * 8; ++j) a[j] += f[j];
        }
        float dv = dinv[r];
#pragma unroll
        for (int j = 0; j < VPT * 8; ++j) a[j] *= dv;
        uint4* dst4 = (uint4*)(tile + (tid >> 2) * SC + g * VPT * 8);
#pragma unroll
        for (int v = 0; v < VPT; ++v) dst4[v] = pack8(a + v * 8);
    }
    __syncthreads();

    const int lane = threadIdx.x & 63;
    const int w = threadIdx.x >> 6;
    const int l16 = lane & 15;
    const int q = lane >> 4;
    const int colbase = w * 32;
    const int nt0 = colbase >> 4;

    f32x4 acc[WM][WN];
#pragma unroll
    for (int wm = 0; wm < WM; ++wm)
#pragma unroll
        for (int nt = 0; nt < WN; ++nt) acc[wm][nt] = (f32x4){0.f, 0.f, 0.f, 0.f};

    const bf16x8* __restrict__ wpl = wp + lane;

#pragma unroll
    for (int kc = 0; kc < NK; ++kc) {
        bf16x8 a[WM];
#pragma unroll
        for (int wm = 0; wm < WM; ++wm)
            a[wm] = *(const bf16x8*)(tile + (wm * 16 + l16) * SC + kc * 32 + q * 8);
        bf16x8 b[WN];
#pragma unroll
        for (int nt = 0; nt < WN; ++nt)
            b[nt] = wpl[(kc * NT + nt0 + nt) * 64];
#pragma unroll
        for (int wm = 0; wm < WM; ++wm)
#pragma unroll
            for (int nt = 0; nt < WN; ++nt)
                acc[wm][nt] = __builtin_amdgcn_mfma_f32_16x16x32_bf16(a[wm], b[nt], acc[wm][nt], 0, 0, 0);
    }

#pragma unroll
    for (int wm = 0; wm < WM; ++wm) {
#pragma unroll
        for (int nt = 0; nt < WN; ++nt) {
            int col = colbase + nt * 16 + l16;
            float bi = bias[col];
#pragma unroll
            for (int r = 0; r < 4; ++r) {
                int row = R0 + wm * 16 + q * 4 + r;
                float v = acc[wm][nt][r] + bi;
                if (RELU) v = fmaxf(v, 0.0f);
                y[(long)row * COUT + col] = f2bf(v);
            }
        }
    }
}

// ================= MFMA conv1d (temporal conv1, proven) =================
template<int CIN, int COUT, int TAPS, bool RELU, bool BIAS, bool SOUT>
__global__ __launch_bounds__(256) void k_mm(const unsigned short* __restrict__ x,
                                            const bf16x8* __restrict__ wp,
                                            const float* __restrict__ bias,
                                            const float* __restrict__ dinv,
                                            unsigned short* __restrict__ y) {
    constexpr int ROWS = 64;
    constexpr int HALO = (TAPS == 3) ? 1 : 0;
    constexpr int TR = ROWS + 2 * HALO;
    constexpr int SC = CIN + 8;
    constexpr int NCH = CIN / 32;
    constexpr int NK = TAPS * NCH;
    constexpr int NT = COUT / 16;
    constexpr int WN = (COUT == 128) ? 2 : 1;
    constexpr int WM = (COUT == 128) ? 4 : 2;
    __shared__ __attribute__((aligned(16))) unsigned short tile[TR * SC];

    const int R0 = blockIdx.x * ROWS;
    const int n0 = R0 & NMASK; (void)n0;

    constexpr int NLD = TR * (CIN / 8);
    for (int idx = threadIdx.x; idx < NLD; idx += 256) {
        int tr = idx / (CIN / 8);
        int c8 = idx - tr * (CIN / 8);
        int ro = tr - HALO;
        bool valid = true;
        if (TAPS == 3) {
            if (ro < 0) valid = (n0 > 0);
            else if (ro >= ROWS) valid = (n0 + ROWS < 4096);
        }
        uint4 v = make_uint4(0, 0, 0, 0);
        if (valid) v = *(const uint4*)(x + (long)(R0 + ro) * CIN + c8 * 8);
        *(uint4*)(tile + tr * SC + c8 * 8) = v;
    }
    __syncthreads();

    const int lane = threadIdx.x & 63;
    const int w = threadIdx.x >> 6;
    const int l16 = lane & 15;
    const int q = lane >> 4;
    const int colbase = (COUT == 128) ? w * 32 : (w & 1) * 16;
    const int rowbase = (COUT == 128) ? 0 : (w >> 1) * 32;
    const int nt0 = colbase >> 4;

    f32x4 acc[WM][WN];
#pragma unroll
    for (int wm = 0; wm < WM; ++wm)
#pragma unroll
        for (int nt = 0; nt < WN; ++nt) acc[wm][nt] = (f32x4){0.f, 0.f, 0.f, 0.f};

    const bf16x8* __restrict__ wpl = wp + lane;

#pragma unroll
    for (int kc = 0; kc < NK; ++kc) {
        const int tap = (TAPS == 3) ? (kc / NCH) : 0;
        const int ch  = (TAPS == 3) ? (kc - tap * NCH) : kc;
        bf16x8 a[WM];
#pragma unroll
        for (int wm = 0; wm < WM; ++wm)
            a[wm] = *(const bf16x8*)(tile + (rowbase + wm * 16 + l16 + tap) * SC + ch * 32 + q * 8);
        bf16x8 b[WN];
#pragma unroll
        for (int nt = 0; nt < WN; ++nt)
            b[nt] = wpl[(kc * NT + nt0 + nt) * 64];
#pragma unroll
        for (int wm = 0; wm < WM; ++wm)
#pragma unroll
            for (int nt = 0; nt < WN; ++nt)
                acc[wm][nt] = __builtin_amdgcn_mfma_f32_16x16x32_bf16(a[wm], b[nt], acc[wm][nt], 0, 0, 0);
    }

#pragma unroll
    for (int wm = 0; wm < WM; ++wm) {
#pragma unroll
        for (int nt = 0; nt < WN; ++nt) {
            int col = colbase + nt * 16 + l16;
            float bi = BIAS ? bias[col] : 0.0f;
#pragma unroll
            for (int r = 0; r < 4; ++r) {
                int row = R0 + rowbase + wm * 16 + q * 4 + r;
                float v = acc[wm][nt][r] + bi;
                if (RELU) v = fmaxf(v, 0.0f);
                if (SOUT) v *= dinv[row];
                y[(long)row * COUT + col] = f2bf(v);
            }
        }
    }
}

// ================= fused conv2 (128->32) + conv3 (32->128) + heads =================
__global__ __launch_bounds__(256) void k_c23_heads(
    const unsigned short* __restrict__ x,      // conv1 output [TOT,128] bf16
    const bf16x8* __restrict__ wp2, const float* __restrict__ tb2,
    const bf16x8* __restrict__ wp3, const float* __restrict__ tb3,
    const float* __restrict__ Wpi, const float* __restrict__ bpi,
    const float* __restrict__ Wn,  const float* __restrict__ bn,
    const float* __restrict__ Wp,  const float* __restrict__ bp,
    float* __restrict__ out) {
    constexpr int SC1 = 136;
    constexpr int SC2 = 40;
    __shared__ __attribute__((aligned(16))) unsigned short shl[82 * 136 + 66 * 40];
    unsigned short* c1  = shl;                // 82 rows: global [R0-2, R0+80)
    unsigned short* c2  = shl + 82 * 136;     // 66 rows: global [R0-1, R0+65)
    unsigned short* xts = shl;                // alias (c1 dead after conv2)

    const int R0 = blockIdx.x * 64;
    const int n0 = R0 & NMASK;
    const int tid = threadIdx.x;

    for (int i = tid; i < 82 * 16; i += 256) {
        int r = i >> 4;
        int c8 = i & 15;
        int n = n0 - 2 + r;
        uint4 v = make_uint4(0, 0, 0, 0);
        if (n >= 0 && n < 4096)
            v = *(const uint4*)(x + (long)(R0 - 2 + r) * 128 + c8 * 8);
        *(uint4*)(c1 + r * SC1 + c8 * 8) = v;
    }
    __syncthreads();

    const int lane = tid & 63;
    const int w = tid >> 6;
    const int l16 = lane & 15;
    const int q = lane >> 4;

    // ---- conv2: 128->32, 5 row-tiles, wave rts {w, w+4} ----
    for (int rt = w; rt < 5; rt += 4) {
        f32x4 acc[2];
#pragma unroll
        for (int nt = 0; nt < 2; ++nt) acc[nt] = (f32x4){0.f, 0.f, 0.f, 0.f};
        const bf16x8* wpl = wp2 + lane;
#pragma unroll
        for (int kc = 0; kc < 12; ++kc) {
            int tap = kc >> 2, ch = kc & 3;
            bf16x8 a = *(const bf16x8*)(c1 + (16 * rt + l16 + tap) * SC1 + ch * 32 + q * 8);
            bf16x8 b0 = wpl[(kc * 2 + 0) * 64];
            bf16x8 b1 = wpl[(kc * 2 + 1) * 64];
            acc[0] = __builtin_amdgcn_mfma_f32_16x16x32_bf16(a, b0, acc[0], 0, 0, 0);
            acc[1] = __builtin_amdgcn_mfma_f32_16x16x32_bf16(a, b1, acc[1], 0, 0, 0);
        }
#pragma unroll
        for (int nt = 0; nt < 2; ++nt) {
            int col = nt * 16 + l16;
            float bi = tb2[col];
#pragma unroll
            for (int r = 0; r < 4; ++r) {
                int idx = 16 * rt + q * 4 + r;
                if (idx < 66) {
                    int n = n0 - 1 + idx;
                    unsigned short v = 0;
                    if (n >= 0 && n < 4096)
                        v = f2bf(fmaxf(acc[nt][r] + bi, 0.0f));
                    c2[idx * SC2 + col] = v;
                }
            }
        }
    }
    __syncthreads();

    // ---- conv3: 32->128, 4 row-tiles at R0; write xts ----
    {
        f32x4 acc[4][2];
#pragma unroll
        for (int rt = 0; rt < 4; ++rt)
#pragma unroll
            for (int nt = 0; nt < 2; ++nt) acc[rt][nt] = (f32x4){0.f, 0.f, 0.f, 0.f};
        const bf16x8* wpl = wp3 + lane;
#pragma unroll
        for (int kc = 0; kc < 3; ++kc) {
            bf16x8 a[4];
#pragma unroll
            for (int rt = 0; rt < 4; ++rt)
                a[rt] = *(const bf16x8*)(c2 + (16 * rt + l16 + kc) * SC2 + q * 8);
            bf16x8 b[2];
#pragma unroll
            for (int nt = 0; nt < 2; ++nt)
                b[nt] = wpl[(kc * 8 + 2 * w + nt) * 64];
#pragma unroll
            for (int rt = 0; rt < 4; ++rt)
#pragma unroll
                for (int nt = 0; nt < 2; ++nt)
                    acc[rt][nt] = __builtin_amdgcn_mfma_f32_16x16x32_bf16(a[rt], b[nt], acc[rt][nt], 0, 0, 0);
        }
#pragma unroll
        for (int rt = 0; rt < 4; ++rt) {
#pragma unroll
            for (int nt = 0; nt < 2; ++nt) {
                int col = w * 32 + nt * 16 + l16;
                float bi = tb3[col];
#pragma unroll
                for (int r = 0; r < 4; ++r) {
                    int row = 16 * rt + q * 4 + r;
                    xts[row * 130 + col] = f2bf(fmaxf(acc[rt][nt][r] + bi, 0.0f));
                }
            }
        }
    }
    __syncthreads();

    // ---- heads ----
    if (tid < 192) {
        int h = tid >> 6;
        int row = tid & 63;
        const float* Wh = (h == 0) ? Wpi : (h == 1) ? Wn : Wp;
        float s = 0.0f;
        const unsigned short* xr = xts + row * 130;
#pragma unroll
        for (int c2i = 0; c2i < 64; ++c2i) {
            unsigned u = *(const unsigned*)(xr + c2i * 2);
            s = fmaf(bf2f(u & 0xffffu), Wh[c2i * 2], s);
            s = fmaf(bf2f(u >> 16), Wh[c2i * 2 + 1], s);
        }
        float bb = (h == 0) ? bpi[0] : (h == 1) ? bn[0] : bp[0];
        float z = s + bb;
        float o;
        if (h == 1) o = (z > 20.0f) ? z : log1pf(expf(z));
        else        o = 1.0f / (1.0f + expf(-z));
        out[h * TOT + R0 + row] = o;
    }
}

extern "C" void kernel_launch(void* const* d_in, const int* in_sizes, int n_in,
                              void* d_out, int out_size, void* d_ws, size_t ws_size,
                              hipStream_t stream) {
    const float* x   = (const float*)d_in[0];
    const int*   ei  = (const int*)d_in[1];
    const int*   src = ei;
    const int*   dst = ei + NE;
    const float* W1 = (const float*)d_in[3];
    const float* b1 = (const float*)d_in[4];
    const float* W2 = (const float*)d_in[5];
    const float* b2 = (const float*)d_in[6];
    const float* W3 = (const float*)d_in[7];
    const float* b3 = (const float*)d_in[8];
    const float* tW1 = (const float*)d_in[9];
    const float* tb1 = (const float*)d_in[10];
    const float* tW2 = (const float*)d_in[11];
    const float* tb2 = (const float*)d_in[12];
    const float* tW3 = (const float*)d_in[13];
    const float* tb3 = (const float*)d_in[14];
    const float* Wpi = (const float*)d_in[15];
    const float* bpi = (const float*)d_in[16];
    const float* Wn  = (const float*)d_in[17];
    const float* bn  = (const float*)d_in[18];
    const float* Wp  = (const float*)d_in[19];
    const float* bp  = (const float*)d_in[20];

    // ---- workspace layout ----
    char* ws = (char*)d_ws;
    float* dinv = (float*)(ws + (0ull << 20));            // 512 KB
    int*   gcur = (int*)  (ws + (1ull << 20));            // 64 KB (line-padded)
    int2*  rse  = (int2*) (ws + (1ull << 20) + (256 << 10)); // 1 MB
    unsigned short* wpG1 = (unsigned short*)(ws + (3ull << 20));
    unsigned short* wpG2 = (unsigned short*)(ws + (3ull << 20) + (128 << 10));
    unsigned short* wpG3 = (unsigned short*)(ws + (3ull << 20) + (256 << 10));
    unsigned short* wpC1 = (unsigned short*)(ws + (3ull << 20) + (384 << 10));
    unsigned short* wpC2 = (unsigned short*)(ws + (3ull << 20) + (512 << 10));
    unsigned short* wpC3 = (unsigned short*)(ws + (3ull << 20) + (640 << 10));
    unsigned* buf = (unsigned*)(ws + (4ull << 20));       // 8 MB
    int* adj = (int*)(ws + (12ull << 20));                // 8 MB
    unsigned short* Xa = (unsigned short*)(ws + (24ull  << 20));  // 64ch  16.8 MB
    unsigned short* Xb = (unsigned short*)(ws + (44ull  << 20));  // 128ch 33.6 MB
    unsigned short* Xc = (unsigned short*)(ws + (80ull  << 20));  // 128ch 33.6 MB
    unsigned short* Xd = (unsigned short*)(ws + (116ull << 20));  // 32ch   8.4 MB
    unsigned short* Xe = (unsigned short*)(ws + (128ull << 20));  // 32ch   8.4 MB

    // ---- prep ----
    hipMemsetAsync(gcur, 0, NB * 32 * sizeof(int), stream);

    // ---- adjacency: bucket partition (+ fused weight packing) + per-bucket CSR ----
    PackArgs pa = { W1, W2, W3, tW1, tW2, tW3, wpG1, wpG2, wpG3, wpC1, wpC2, wpC3 };
    k_part<<<NE / EPB, 256, 0, stream>>>(src, dst, gcur, buf, pa);
    k_bcsr<<<NB, 256, 0, stream>>>(buf, gcur, adj, rse, dinv, (const float4*)x, (uint4*)Xa);

    // ---- GCN layers 1+2a fused: gather + GEMM1 + GEMM2 -> zs2 (h1 never hits HBM) ----
    k_gmm2<<<TOT / 64, 256, 0, stream>>>((const uint4*)Xa, adj, rse, dinv,
                                         (const bf16x8*)wpG1, b1, (const bf16x8*)wpG2, Xd);

    // ---- GCN layer 2b: zs3 = relu(agg(zs2)*dinv + b2)*dinv ----
    k_gcsr<2><<<TOT * 4 / 256, 256, 0, stream>>>((const uint4*)Xd, adj, rse, dinv,
                                                 b2, (uint4*)Xe);

    // ---- GCN layer 3: fused gather+GEMM -> h3 ----
    k_gmm<32, true><<<TOT / 64, 256, 0, stream>>>((const uint4*)Xe, adj, rse, dinv,
                                                  (const bf16x8*)wpG3, b3, Xb);

    // ---- temporal conv1 (standalone, proven) ----
    k_mm<128, 128, 3, true, true, false>
        <<<TOT / 64, 256, 0, stream>>>(Xb, (const bf16x8*)wpC1, tb1, nullptr, Xc);

    // ---- conv2 + conv3 + heads fused ----
    k_c23_heads<<<TOT / 64, 256, 0, stream>>>(Xc,
                                              (const bf16x8*)wpC2, tb2,
                                              (const bf16x8*)wpC3, tb3,
                                              Wpi, bpi, Wn, bn, Wp, bp, (float*)d_out);
}